// Round 9
// baseline (467.705 us; speedup 1.0000x reference)
//
#include <hip/hip_runtime.h>
#include <hip/hip_bf16.h>
#include <math.h>

// ---------------- problem constants ----------------
#define HID    2048
#define NH     16
#define D_NOPE 128
#define D_ROPE 64
#define HD     192      // HEAD_DIM
#define V_DIM  128
#define KV_RANK 512
#define Q_RANK  1536
#define BATCH  2
#define SEQ    2048
#define ROWS   (BATCH*SEQ)   // 4096

typedef __attribute__((ext_vector_type(8))) short short8;
typedef __attribute__((ext_vector_type(4))) float f32x4;

__device__ __forceinline__ unsigned short f2bf(float x) {
    unsigned int u = __float_as_uint(x);
    unsigned int r = (u + 0x7fffu + ((u >> 16) & 1u)) >> 16;
    return (unsigned short)r;
}
__device__ __forceinline__ float bf2f(unsigned short u) {
    return __uint_as_float((unsigned int)u << 16);
}

typedef const __attribute__((address_space(1))) unsigned int gu32;
typedef __attribute__((address_space(3))) unsigned int lu32;
__device__ __forceinline__ void gl_lds16(const void* g, void* l) {
    __builtin_amdgcn_global_load_lds((gu32*)g, (lu32*)l, 16, 0, 0);
}

// DPP lane permute within a 16-lane row (VALU pipe, no LDS traffic)
template<int CTRL>
__device__ __forceinline__ float dpp_mv(float x) {
    return __int_as_float(__builtin_amdgcn_update_dpp(
        __float_as_int(x), __float_as_int(x), CTRL, 0xF, 0xF, true));
}
// max over the 16 contiguous lanes of a DPP row
__device__ __forceinline__ float rowmax16(float x) {
    x = fmaxf(x, dpp_mv<0xB1>(x));   // quad_perm [1,0,3,2]  (xor 1)
    x = fmaxf(x, dpp_mv<0x4E>(x));   // quad_perm [2,3,0,1]  (xor 2)
    x = fmaxf(x, dpp_mv<0x141>(x));  // row_half_mirror      (combine quads)
    x = fmaxf(x, dpp_mv<0x140>(x));  // row_mirror           (combine halves)
    return x;
}

// ---------------- fused preprocessing: rope table + x->bf16 + 5 transposes ---
__global__ __launch_bounds__(256) void preprocess_kernel(
    const float* __restrict__ x,
    const float* __restrict__ w_q_down, const float* __restrict__ w_q_up,
    const float* __restrict__ w_kv_down, const float* __restrict__ w_kv_up,
    const float* __restrict__ w_out,
    float* __restrict__ table, unsigned short* __restrict__ xb,
    unsigned short* __restrict__ wt1, unsigned short* __restrict__ wt2,
    unsigned short* __restrict__ wt3, unsigned short* __restrict__ wt4,
    unsigned short* __restrict__ wt5)
{
    const int tid = threadIdx.x;
    int bid = blockIdx.x;

    if (bid < 512) {                       // ---- RoPE cos/sin table ----
        int idx = bid * 256 + tid;         // < 2048*64
        int pos = idx >> 6, u = idx & 63;
        int i = u & 31;
        float invf = expf((float)i * (-9.210340371976184f / 32.0f));
        float ang = (float)pos * invf;
        table[idx] = (u < 32) ? cosf(ang) : sinf(ang);
        return;
    }
    bid -= 512;
    if (bid < 8192) {                      // ---- x fp32 -> bf16 ----
        size_t i = (size_t)(bid * 256 + tid) * 4;
        float4 v = *(const float4*)(x + i);
        ushort4 u;
        u.x = f2bf(v.x); u.y = f2bf(v.y); u.z = f2bf(v.z); u.w = f2bf(v.w);
        *(ushort4*)(xb + i) = u;
        return;
    }
    bid -= 8192;

    // ---- weight transposes: fp32 (K x N) -> bf16 (N x K) ----
    const float* src; unsigned short* dst; int K, N, gx, lb;
    if (bid < 768)       { src = w_q_down;  dst = wt1; K = 2048; N = 1536; gx = 24; lb = bid; }
    else if (bid < 1920) { src = w_q_up;    dst = wt2; K = 1536; N = 3072; gx = 48; lb = bid - 768; }
    else if (bid < 2208) { src = w_kv_down; dst = wt3; K = 2048; N = 576;  gx = 9;  lb = bid - 1920; }
    else if (bid < 2720) { src = w_kv_up;   dst = wt4; K = 512;  N = 4096; gx = 64; lb = bid - 2208; }
    else                 { src = w_out;     dst = wt5; K = 2048; N = 2048; gx = 32; lb = bid - 2720; }
    const int n0 = (lb % gx) * 64, k0 = (lb / gx) * 64;

    __shared__ float T[64][65];
    const int c4 = tid & 15, r = tid >> 4;
    #pragma unroll
    for (int i = 0; i < 4; i++) {
        int row = r + i * 16;
        float4 v = *(const float4*)(src + (size_t)(k0 + row) * N + n0 + c4 * 4);
        T[row][c4*4+0] = v.x; T[row][c4*4+1] = v.y;
        T[row][c4*4+2] = v.z; T[row][c4*4+3] = v.w;
    }
    __syncthreads();
    #pragma unroll
    for (int i = 0; i < 4; i++) {
        int nrow = r + i * 16;
        ushort4 u;
        u.x = f2bf(T[c4*4+0][nrow]); u.y = f2bf(T[c4*4+1][nrow]);
        u.z = f2bf(T[c4*4+2][nrow]); u.w = f2bf(T[c4*4+3][nrow]);
        *(ushort4*)(dst + (size_t)(n0 + nrow) * K + k0 + c4 * 4) = u;
    }
}

// ---------------- bf16 MFMA GEMM body: C(M,N) = A(M,K) @ Bt(N,K)^T ----------
// Templated on BM (64/128) x BN (64/128).  Per-sub-grid bijective XCD
// m-cluster swizzle (all sub-grid sizes divisible by 8).  VSTORE: for the
// kv_up GEMM, v-tiles (odd n0/128) are written TRANSPOSED into Vmat instead
// of kv_exp_b (flash never reads v columns) -- pack_vt kernel eliminated.
extern __shared__ unsigned short smem_gemm[];   // <= 16 KB

template<int BM, int BN, bool OUT_BF16, bool VSTORE>
__device__ __forceinline__ void bgemm_body(
    int rbid, int nb,
    const unsigned short* __restrict__ A,    // M x K bf16
    const unsigned short* __restrict__ Bt,   // N x K bf16
    void* __restrict__ Cv,                   // M x N (fp32 or bf16)
    unsigned short* __restrict__ vmat,       // used when VSTORE
    int M, int N, int K)
{
    constexpr int MT = BM / 32;              // m-subtiles per wave
    constexpr int NT = BN / 32;
    constexpr int NSLAB = BM / 16 + BN / 16;
    const int tid  = threadIdx.x;
    const int w    = tid >> 6;
    const int lane = tid & 63;
    const int n16  = lane & 15, quad = lane >> 4;

    const int T8   = nb >> 3;                      // blocks per XCD
    const int nbid = (rbid & 7) * T8 + (rbid >> 3);
    const int gx   = N / BN;
    const int m0 = (nbid / gx) * BM;
    const int n0 = (nbid % gx) * BN;
    const int moff = (w & 1) * (MT * 16);
    const int noff = (w >> 1) * (NT * 16);

    unsigned short* As = smem_gemm;            // BM*32
    unsigned short* Bs = smem_gemm + BM*32;    // BN*32

    const unsigned short* gp[4];
    unsigned short* lp[4];
    int ns = 0;
    const int rl = lane >> 2, sc = lane & 3;
    for (int s = w; s < NSLAB; s += 4) {
        int kc = sc ^ (((s * 16 + rl) >> 1) & 3);   // XOR swizzle
        if (s < BM/16) {
            gp[ns] = A + (size_t)(m0 + s * 16 + rl) * K + kc * 8;
            lp[ns] = As + s * 512;
        } else {
            int sb = s - BM/16;
            gp[ns] = Bt + (size_t)(n0 + sb * 16 + rl) * K + kc * 8;
            lp[ns] = Bs + sb * 512;
        }
        ns++;
    }

    const int swz = (quad ^ ((n16 >> 1) & 3)) * 8;
    int aoff[MT], boff[NT];
    #pragma unroll
    for (int mt = 0; mt < MT; mt++) aoff[mt] = (moff + mt * 16 + n16) * 32 + swz;
    #pragma unroll
    for (int nt = 0; nt < NT; nt++) boff[nt] = (noff + nt * 16 + n16) * 32 + swz;

    f32x4 acc[MT][NT];
    #pragma unroll
    for (int mt = 0; mt < MT; mt++)
        #pragma unroll
        for (int nt = 0; nt < NT; nt++) acc[mt][nt] = (f32x4){0.f, 0.f, 0.f, 0.f};

    for (int k0 = 0; k0 < K; k0 += 32) {
        #pragma unroll
        for (int j = 0; j < 4; j++) if (j < ns) gl_lds16(gp[j], lp[j]);
        #pragma unroll
        for (int j = 0; j < 4; j++) if (j < ns) gp[j] += 32;
        __syncthreads();

        short8 af[MT], bfr[NT];
        #pragma unroll
        for (int mt = 0; mt < MT; mt++) af[mt] = *(const short8*)(As + aoff[mt]);
        #pragma unroll
        for (int nt = 0; nt < NT; nt++) bfr[nt] = *(const short8*)(Bs + boff[nt]);
        #pragma unroll
        for (int mt = 0; mt < MT; mt++)
            #pragma unroll
            for (int nt = 0; nt < NT; nt++)
                acc[mt][nt] = __builtin_amdgcn_mfma_f32_16x16x32_bf16(
                    af[mt], bfr[nt], acc[mt][nt], 0, 0, 0);
        __syncthreads();
    }

    if (VSTORE && ((n0 >> 7) & 1)) {
        // v-tile: write transposed into Vmat [b][h][d][token]
        const int hh = n0 >> 8;
        #pragma unroll
        for (int mt = 0; mt < MT; mt++) {
            int token = m0 + moff + mt * 16 + quad * 4;
            int bb = token >> 11, ti = token & (SEQ - 1);
            unsigned short* vb = vmat + (size_t)(bb*NH + hh) * V_DIM * SEQ + ti;
            #pragma unroll
            for (int nt = 0; nt < NT; nt++) {
                int d = noff + nt * 16 + n16;
                ushort4 u;
                u.x = f2bf(acc[mt][nt][0]); u.y = f2bf(acc[mt][nt][1]);
                u.z = f2bf(acc[mt][nt][2]); u.w = f2bf(acc[mt][nt][3]);
                *(ushort4*)(vb + (size_t)d * SEQ) = u;
            }
        }
        return;
    }

    #pragma unroll
    for (int mt = 0; mt < MT; mt++)
        #pragma unroll
        for (int nt = 0; nt < NT; nt++)
            #pragma unroll
            for (int r = 0; r < 4; r++) {
                size_t idx = (size_t)(m0 + moff + mt * 16 + quad * 4 + r) * N
                           + n0 + noff + nt * 16 + n16;
                if (OUT_BF16) ((unsigned short*)Cv)[idx] = f2bf(acc[mt][nt][r]);
                else          ((float*)Cv)[idx] = acc[mt][nt][r];
            }
}

// stage1: q_down (768 blk, BM=64) || kv_down (576 blk, BM=64)
__global__ __launch_bounds__(256) void gemm_stage1_kernel(
    const unsigned short* __restrict__ xb,
    const unsigned short* __restrict__ wt1, const unsigned short* __restrict__ wt3,
    unsigned short* __restrict__ qdb, float* __restrict__ kv_full)
{
    if (blockIdx.x < 768)
        bgemm_body<64, 128, true, false>(blockIdx.x, 768, xb, wt1, qdb, nullptr, ROWS, 1536, 2048);
    else
        bgemm_body<64, 64, false, false>(blockIdx.x - 768, 576, xb, wt3, kv_full, nullptr, ROWS, 576, 2048);
}

// stage2: q_up (768 blk) || kv_up (1024 blk, v-tiles -> Vmat transposed)
__global__ __launch_bounds__(256) void gemm_stage2_kernel(
    const unsigned short* __restrict__ qdb, const unsigned short* __restrict__ wt2,
    const unsigned short* __restrict__ kv_cb, const unsigned short* __restrict__ wt4,
    unsigned short* __restrict__ qb16, unsigned short* __restrict__ kv_exp_b,
    unsigned short* __restrict__ Vmat)
{
    if (blockIdx.x < 768)
        bgemm_body<128, 128, true, false>(blockIdx.x, 768, qdb, wt2, qb16, nullptr, ROWS, 3072, 1536);
    else
        bgemm_body<128, 128, true, true>(blockIdx.x - 768, 1024, kv_cb, wt4, kv_exp_b, Vmat, ROWS, 4096, 512);
}

// output projection (BM=64 -> 1024 blocks, 4/CU)
__global__ __launch_bounds__(256) void gemm_out_kernel(
    const unsigned short* __restrict__ attnb, const unsigned short* __restrict__ wt5,
    float* __restrict__ out)
{
    bgemm_body<64, 128, false, false>(blockIdx.x, 1024, attnb, wt5, out, nullptr, ROWS, 2048, 2048);
}

// ---------------- RMSNorm(kv_c)->bf16 + RoPE(k_rope)->bf16 ----------------
__global__ __launch_bounds__(256) void kv_norm_rope_kernel(
    const float* __restrict__ kv_full,    // (4096, 576)
    const float* __restrict__ w,          // (512,)
    const float* __restrict__ table,
    unsigned short* __restrict__ kv_cb,   // (4096, 512) bf16
    unsigned short* __restrict__ k_rope_b)// (4096, 64) bf16 roped
{
    const int row = blockIdx.x;
    const int tid = threadIdx.x;
    const float* src = kv_full + (size_t)row * 576;
    float v0 = src[tid], v1 = src[tid + 256];
    float ss = v0*v0 + v1*v1;
    #pragma unroll
    for (int off = 32; off > 0; off >>= 1) ss += __shfl_down(ss, off);
    __shared__ float red[4];
    __shared__ float msh;
    if ((tid & 63) == 0) red[tid >> 6] = ss;
    __syncthreads();
    if (tid == 0) msh = (red[0] + red[1] + red[2] + red[3]) * (1.0f / 512.0f);
    __syncthreads();
    float f = rsqrtf(msh + 1e-6f);
    kv_cb[(size_t)row * 512 + tid]       = f2bf(v0 * f * w[tid]);
    kv_cb[(size_t)row * 512 + tid + 256] = f2bf(v1 * f * w[tid + 256]);
    if (tid < 32) {
        int pos = row & (SEQ - 1);
        float c = table[pos*64 + tid], s = table[pos*64 + 32 + tid];
        float x1 = src[512 + tid], x2 = src[512 + 32 + tid];
        k_rope_b[(size_t)row * 64 + tid]      = f2bf(x1*c - x2*s);
        k_rope_b[(size_t)row * 64 + 32 + tid] = f2bf(x2*c + x1*s);
    }
}

// ---------------- MFMA flash attention, 4-wave QBLK=64, double-buffered ------
// R7/R8 structure unchanged (proven 119 us).
__global__ __launch_bounds__(256, 3) void flash_mfma_kernel(
    const unsigned short* __restrict__ qb16,     // (4096, 3072) RAW q bf16
    const unsigned short* __restrict__ kv_exp_b, // (4096, 4096) bf16 (k-nope cols)
    const unsigned short* __restrict__ k_rope_b, // (4096, 64) bf16 roped
    const unsigned short* __restrict__ Vmat,     // [b][h][128][2048] bf16
    const float* __restrict__ table,             // (2048, 64) cos/sin
    unsigned short* __restrict__ attnb)          // (4096, 2048) bf16
{
    const int bid  = blockIdx.x;
    const int xcd  = bid & 7, slot = bid >> 3;   // XCD-clustered remap
    const int grp  = xcd + 8 * (slot >> 5);      // (b,h) group 0..31
    const int qb   = 31 - (slot & 31);           // longest blocks first
    const int h    = grp & 15, b = grp >> 4;
    const int tid  = threadIdx.x;
    const int w    = tid >> 6;
    const int lane = tid & 63;
    const int n16  = lane & 15;
    const int quad = lane >> 4;

    const int q0 = qb * 64 + w * 16;             // this wave's 16 q rows
    const char* kNopeB = (const char*)(kv_exp_b + (size_t)b * SEQ * 4096 + h * 256);
    const char* kRopeB = (const char*)(k_rope_b + (size_t)b * SEQ * 64);
    const char* vByte  = (const char*)(Vmat + (size_t)(b*NH + h) * V_DIM * SEQ);

    __shared__ unsigned short Ks[2][6144];       // 2 x 12 KB: 32 keys x 192
    __shared__ unsigned short Vs[2][4096];       // 2 x 8 KB: 128 d x 32 keys
    __shared__ unsigned short Plds[4][16][40];   // 5 KB

    // ---- per-thread staging source pointers (advance by k0 per tile) ----
    const char* gK[2]; int lK[2];
    #pragma unroll
    for (int t = 0; t < 2; t++) {
        int idx = t * 256 + tid;                 // 0..511
        int kc = idx >> 7, key = (idx >> 2) & 31, sc = idx & 3;
        int scs = sc ^ ((key >> 1) & 3);         // pre-swizzled source
        gK[t] = kNopeB + (size_t)key * 8192 + kc * 64 + scs * 16;
        lK[t] = idx * 16;
    }
    const char* gR; int lR;
    {
        int kc = tid >> 7, key = (tid >> 2) & 31, sc = tid & 3;
        int scs = sc ^ ((key >> 1) & 3);
        gR = kRopeB + (size_t)key * 128 + kc * 64 + scs * 16;
        lR = (512 + tid) * 16;
    }
    const char* gV[2]; int lV[2];
    #pragma unroll
    for (int t = 0; t < 2; t++) {
        int idx = t * 256 + tid;
        int d = idx >> 2, sc = idx & 3;
        int scs = sc ^ ((d >> 1) & 3);
        gV[t] = vByte + (size_t)d * (SEQ * 2) + scs * 16;
        lV[t] = idx * 16;
    }

    auto stage = [&](int kt, int bufsel) {
        const size_t koff = (size_t)kt * 32;
        #pragma unroll
        for (int t = 0; t < 2; t++)
            gl_lds16(gK[t] + koff * 8192, (char*)Ks[bufsel] + lK[t]);
        gl_lds16(gR + koff * 128, (char*)Ks[bufsel] + lR);
        #pragma unroll
        for (int t = 0; t < 2; t++)
            gl_lds16(gV[t] + koff * 2, (char*)Vs[bufsel] + lV[t]);
    };

    // ---- Q fragments from RAW projection output, RoPE applied in-register --
    short8 qf[6];
    {
        const unsigned short* qp = qb16 + ((size_t)(b*SEQ) + q0 + n16) * (NH*HD)
                                 + h * HD + quad * 8;
        #pragma unroll
        for (int kc = 0; kc < 6; kc++)
            qf[kc] = *(const short8*)(qp + kc * 32);
        // rope pair (128+i, 160+i), i = quad*8+j -> qf[4][j], qf[5][j]
        const float* tb = table + (size_t)(q0 + n16) * 64 + quad * 8;
        float4 c0 = *(const float4*)(tb);
        float4 c1 = *(const float4*)(tb + 4);
        float4 s0 = *(const float4*)(tb + 32);
        float4 s1 = *(const float4*)(tb + 36);
        float cs[8] = {c0.x,c0.y,c0.z,c0.w,c1.x,c1.y,c1.z,c1.w};
        float sn[8] = {s0.x,s0.y,s0.z,s0.w,s1.x,s1.y,s1.z,s1.w};
        #pragma unroll
        for (int j = 0; j < 8; j++) {
            float x1 = bf2f((unsigned short)qf[4][j]);
            float x2 = bf2f((unsigned short)qf[5][j]);
            qf[4][j] = (short)f2bf(x1*cs[j] - x2*sn[j]);
            qf[5][j] = (short)f2bf(x2*cs[j] + x1*sn[j]);
        }
    }

    // ones B-frag for the denominator MFMA (bf16 1.0 in every slot)
    short8 onesf;
    #pragma unroll
    for (int j = 0; j < 8; j++) onesf[j] = (short)0x3F80;

    f32x4 O[9];                                  // O[0..7] = out, O[8] = l
    #pragma unroll
    for (int c = 0; c < 9; c++) O[c] = (f32x4){0.f, 0.f, 0.f, 0.f};
    float mrow[4] = {-INFINITY, -INFINITY, -INFINITY, -INFINITY};

    // raw-unit softmax: exp(s*scale - m*scale) = exp2((s - m) * SCLOG2)
    const float SCLOG2 = 0.10412779736150104f;   // (1/sqrt(192))*log2(e)
    const float THRRAW = 83.14f;                 // defer-max: 6 / scale
    const int swz = (quad ^ ((n16 >> 1) & 3)) * 8;
    const int ntB = 2 * qb + 2;                  // 32-key tiles for this block

    stage(0, 0);
    int cur = 0;
    for (int kt = 0; kt < ntB; kt++) {
        __syncthreads();                          // drains stage of buf `cur`
        if (kt + 1 < ntB) stage(kt + 1, cur ^ 1); // prefetch overlaps compute
        const int k0 = kt * 32;

        if (k0 <= q0 + 15) {                      // wave-uniform causal guard
            const unsigned short* KsB = Ks[cur];
            const unsigned short* VsB = Vs[cur];

            // ---- QK^T: two 16-key halves, 6 K-chunks each ----
            f32x4 S[2];
            __builtin_amdgcn_s_setprio(1);
            #pragma unroll
            for (int half = 0; half < 2; half++) {
                f32x4 acc = (f32x4){0.f, 0.f, 0.f, 0.f};
                const int keyoff = (half * 16 + n16) * 32 + swz;
                #pragma unroll
                for (int kc = 0; kc < 6; kc++) {
                    short8 kf = *(const short8*)(KsB + kc * 1024 + keyoff);
                    acc = __builtin_amdgcn_mfma_f32_16x16x32_bf16(qf[kc], kf, acc, 0, 0, 0);
                }
                S[half] = acc;
            }
            __builtin_amdgcn_s_setprio(0);

            // ---- masks only on the diagonal tile (raw units) ----
            float p0[4], p1[4];
            if (k0 + 32 > q0) {
                #pragma unroll
                for (int r = 0; r < 4; r++) {
                    int row = q0 + quad*4 + r;
                    p0[r] = (k0 + n16      <= row) ? S[0][r] : -INFINITY;
                    p1[r] = (k0 + 16 + n16 <= row) ? S[1][r] : -INFINITY;
                }
            } else {
                #pragma unroll
                for (int r = 0; r < 4; r++) { p0[r] = S[0][r]; p1[r] = S[1][r]; }
            }

            // ---- DPP row-max + defer-max (raw units) ----
            float tmax[4];
            float growth = -INFINITY;
            #pragma unroll
            for (int r = 0; r < 4; r++) {
                tmax[r] = rowmax16(fmaxf(p0[r], p1[r]));
                growth = fmaxf(growth, tmax[r] - mrow[r]);
            }
            if (!__all(growth <= THRRAW)) {       // rescale only on real growth
                #pragma unroll
                for (int r = 0; r < 4; r++) {
                    float mnew = fmaxf(mrow[r], tmax[r]);
                    float alpha = exp2f((mrow[r] - mnew) * SCLOG2);
                    mrow[r] = mnew;
                    #pragma unroll
                    for (int c = 0; c < 9; c++) O[c][r] *= alpha;
                }
            }
            #pragma unroll
            for (int r = 0; r < 4; r++) {
                float e0 = exp2f((p0[r] - mrow[r]) * SCLOG2);  // bounded by e^6
                float e1 = exp2f((p1[r] - mrow[r]) * SCLOG2);
                unsigned int pk;
                asm("v_cvt_pk_bf16_f32 %0, %1, %2" : "=v"(pk) : "v"(e0), "v"(e1));
                unsigned short* pw = &Plds[w][quad*4 + r][0];
                pw[n16]      = (unsigned short)(pk & 0xffffu);
                pw[16 + n16] = (unsigned short)(pk >> 16);
            }

            // ---- P as A-frag (per-wave LDS roundtrip), then PV (+l) ----
            short8 pf = *(const short8*)(&Plds[w][n16][quad * 8]);
            __builtin_amdgcn_s_setprio(1);
            #pragma unroll
            for (int c = 0; c < 8; c++) {
                short8 vf = *(const short8*)(VsB + (c * 16 + n16) * 32 + swz);
                O[c] = __builtin_amdgcn_mfma_f32_16x16x32_bf16(pf, vf, O[c], 0, 0, 0);
            }
            O[8] = __builtin_amdgcn_mfma_f32_16x16x32_bf16(pf, onesf, O[8], 0, 0, 0);
            __builtin_amdgcn_s_setprio(0);
        }
        cur ^= 1;
    }

    float invl[4];
    #pragma unroll
    for (int r = 0; r < 4; r++) invl[r] = 1.0f / O[8][r];
    #pragma unroll
    for (int c = 0; c < 8; c++) {
        #pragma unroll
        for (int r = 0; r < 4; r++) {
            size_t tok = (size_t)b * SEQ + q0 + quad*4 + r;
            attnb[tok * (NH*V_DIM) + h * V_DIM + c*16 + n16] = f2bf(O[c][r] * invl[r]);
        }
    }
}

// ---------------- launch ----------------
extern "C" void kernel_launch(void* const* d_in, const int* in_sizes, int n_in,
                              void* d_out, int out_size, void* d_ws, size_t ws_size,
                              hipStream_t stream)
{
    const float* x         = (const float*)d_in[0];
    const float* w_q_down  = (const float*)d_in[1];
    const float* w_q_up    = (const float*)d_in[2];
    const float* w_kv_down = (const float*)d_in[3];
    const float* kv_norm_w = (const float*)d_in[4];
    const float* w_kv_up   = (const float*)d_in[5];
    const float* w_out     = (const float*)d_in[6];
    float* out = (float*)d_out;
    float* ws  = (float*)d_ws;

    // ---- workspace layout (float offsets), total 41,746,432 floats (~167 MB) ----
    float*          table    = ws;                                // 131072
    unsigned short* xb       = (unsigned short*)(ws + 131072);    // 4096x2048 bf16
    unsigned short* qdb      = (unsigned short*)(ws + 4325376);   // 4096x1536 bf16
    unsigned short* qb16     = (unsigned short*)(ws + 7471104);   // 4096x3072 bf16
    float*          kv_full  = ws + 13762560;                     // 4096x576 fp32
    unsigned short* kv_cb    = (unsigned short*)(ws + 16121856);  // 4096x512 bf16
    unsigned short* k_rope_b = (unsigned short*)(ws + 17170432);  // 4096x64 bf16
    unsigned short* kv_exp_b = (unsigned short*)(ws + 17301504);  // 4096x4096 bf16
    unsigned short* Vmat     = (unsigned short*)(ws + 25690112);  // 2x16x128x2048 bf16
    unsigned short* attnb    = (unsigned short*)(ws + 29884416);  // 4096x2048 bf16
    unsigned short* wt1      = (unsigned short*)(ws + 34078720);  // 1536x2048
    unsigned short* wt2      = (unsigned short*)(ws + 35651584);  // 3072x1536
    unsigned short* wt3      = (unsigned short*)(ws + 38010880);  // 576x2048
    unsigned short* wt4      = (unsigned short*)(ws + 38600704);  // 4096x512
    unsigned short* wt5      = (unsigned short*)(ws + 39649280);  // 2048x2048 -> end 41746432

    // all independent preprocessing in ONE launch
    preprocess_kernel<<<dim3(12448), 256, 0, stream>>>(
        x, w_q_down, w_q_up, w_kv_down, w_kv_up, w_out,
        table, xb, wt1, wt2, wt3, wt4, wt5);

    // stage1: q_down || kv_down, BM=64 (1344 blocks, ~5/CU)
    gemm_stage1_kernel<<<dim3(1344), 256, 16384, stream>>>(xb, wt1, wt3, qdb, kv_full);

    kv_norm_rope_kernel<<<ROWS, 256, 0, stream>>>(kv_full, kv_norm_w, table, kv_cb, k_rope_b);

    // stage2: q_up || kv_up (v-tiles written transposed into Vmat; pack_vt gone)
    gemm_stage2_kernel<<<dim3(1792), 256, 16384, stream>>>(qdb, wt2, kv_cb, wt4, qb16, kv_exp_b, Vmat);

    // attention (R7 structure, unchanged)
    flash_mfma_kernel<<<dim3(1024), 256, 0, stream>>>(qb16, kv_exp_b, k_rope_b, Vmat, table, attnb);

    // output projection, BM=64 (1024 blocks, 4/CU)
    gemm_out_kernel<<<dim3(1024), 256, 16384, stream>>>(attnb, wt5, out);
}

// Round 10
// 435.332 us; speedup vs baseline: 1.0744x; 1.0744x over previous
//
#include <hip/hip_runtime.h>
#include <hip/hip_bf16.h>
#include <math.h>

// ---------------- problem constants ----------------
#define HID    2048
#define NH     16
#define D_NOPE 128
#define D_ROPE 64
#define HD     192      // HEAD_DIM
#define V_DIM  128
#define KV_RANK 512
#define Q_RANK  1536
#define BATCH  2
#define SEQ    2048
#define ROWS   (BATCH*SEQ)   // 4096

typedef __attribute__((ext_vector_type(8))) short short8;
typedef __attribute__((ext_vector_type(4))) float f32x4;

__device__ __forceinline__ unsigned short f2bf(float x) {
    unsigned int u = __float_as_uint(x);
    unsigned int r = (u + 0x7fffu + ((u >> 16) & 1u)) >> 16;
    return (unsigned short)r;
}
__device__ __forceinline__ float bf2f(unsigned short u) {
    return __uint_as_float((unsigned int)u << 16);
}

typedef const __attribute__((address_space(1))) unsigned int gu32;
typedef __attribute__((address_space(3))) unsigned int lu32;
__device__ __forceinline__ void gl_lds16(const void* g, void* l) {
    __builtin_amdgcn_global_load_lds((gu32*)g, (lu32*)l, 16, 0, 0);
}

// DPP lane permute within a 16-lane row (VALU pipe, no LDS traffic)
template<int CTRL>
__device__ __forceinline__ float dpp_mv(float x) {
    return __int_as_float(__builtin_amdgcn_update_dpp(
        __float_as_int(x), __float_as_int(x), CTRL, 0xF, 0xF, true));
}
// max over the 16 contiguous lanes of a DPP row
__device__ __forceinline__ float rowmax16(float x) {
    x = fmaxf(x, dpp_mv<0xB1>(x));   // quad_perm [1,0,3,2]  (xor 1)
    x = fmaxf(x, dpp_mv<0x4E>(x));   // quad_perm [2,3,0,1]  (xor 2)
    x = fmaxf(x, dpp_mv<0x141>(x));  // row_half_mirror      (combine quads)
    x = fmaxf(x, dpp_mv<0x140>(x));  // row_mirror           (combine halves)
    return x;
}

// ---------------- fused preprocessing: rope table + x->bf16 + 5 transposes ---
__global__ __launch_bounds__(256) void preprocess_kernel(
    const float* __restrict__ x,
    const float* __restrict__ w_q_down, const float* __restrict__ w_q_up,
    const float* __restrict__ w_kv_down, const float* __restrict__ w_kv_up,
    const float* __restrict__ w_out,
    float* __restrict__ table, unsigned short* __restrict__ xb,
    unsigned short* __restrict__ wt1, unsigned short* __restrict__ wt2,
    unsigned short* __restrict__ wt3, unsigned short* __restrict__ wt4,
    unsigned short* __restrict__ wt5)
{
    const int tid = threadIdx.x;
    int bid = blockIdx.x;

    if (bid < 512) {                       // ---- RoPE cos/sin table ----
        int idx = bid * 256 + tid;         // < 2048*64
        int pos = idx >> 6, u = idx & 63;
        int i = u & 31;
        float invf = expf((float)i * (-9.210340371976184f / 32.0f));
        float ang = (float)pos * invf;
        table[idx] = (u < 32) ? cosf(ang) : sinf(ang);
        return;
    }
    bid -= 512;
    if (bid < 8192) {                      // ---- x fp32 -> bf16 ----
        size_t i = (size_t)(bid * 256 + tid) * 4;
        float4 v = *(const float4*)(x + i);
        ushort4 u;
        u.x = f2bf(v.x); u.y = f2bf(v.y); u.z = f2bf(v.z); u.w = f2bf(v.w);
        *(ushort4*)(xb + i) = u;
        return;
    }
    bid -= 8192;

    // ---- weight transposes: fp32 (K x N) -> bf16 (N x K) ----
    const float* src; unsigned short* dst; int K, N, gx, lb;
    if (bid < 768)       { src = w_q_down;  dst = wt1; K = 2048; N = 1536; gx = 24; lb = bid; }
    else if (bid < 1920) { src = w_q_up;    dst = wt2; K = 1536; N = 3072; gx = 48; lb = bid - 768; }
    else if (bid < 2208) { src = w_kv_down; dst = wt3; K = 2048; N = 576;  gx = 9;  lb = bid - 1920; }
    else if (bid < 2720) { src = w_kv_up;   dst = wt4; K = 512;  N = 4096; gx = 64; lb = bid - 2208; }
    else                 { src = w_out;     dst = wt5; K = 2048; N = 2048; gx = 32; lb = bid - 2720; }
    const int n0 = (lb % gx) * 64, k0 = (lb / gx) * 64;

    __shared__ float T[64][65];
    const int c4 = tid & 15, r = tid >> 4;
    #pragma unroll
    for (int i = 0; i < 4; i++) {
        int row = r + i * 16;
        float4 v = *(const float4*)(src + (size_t)(k0 + row) * N + n0 + c4 * 4);
        T[row][c4*4+0] = v.x; T[row][c4*4+1] = v.y;
        T[row][c4*4+2] = v.z; T[row][c4*4+3] = v.w;
    }
    __syncthreads();
    #pragma unroll
    for (int i = 0; i < 4; i++) {
        int nrow = r + i * 16;
        ushort4 u;
        u.x = f2bf(T[c4*4+0][nrow]); u.y = f2bf(T[c4*4+1][nrow]);
        u.z = f2bf(T[c4*4+2][nrow]); u.w = f2bf(T[c4*4+3][nrow]);
        *(ushort4*)(dst + (size_t)(n0 + nrow) * K + k0 + c4 * 4) = u;
    }
}

// ---------------- bf16 MFMA GEMM body: C(M,N) = A(M,K) @ Bt(N,K)^T ----------
// BM=128 everywhere (R9's BM=64 experiment REGRESSED: halving BM doubles
// B-panel staging traffic and halves MFMA:stage ratio; these GEMMs are
// staging-throughput-bound, not fill-bound).  Per-sub-grid bijective XCD
// m-cluster swizzle.  VSTORE: kv_up v-tiles (odd n0/128) written TRANSPOSED
// into Vmat (flash never reads v columns) -- pack_vt kernel eliminated.
extern __shared__ unsigned short smem_gemm[];   // <= 16 KB

template<int BM, int BN, bool OUT_BF16, bool VSTORE>
__device__ __forceinline__ void bgemm_body(
    int rbid, int nb,
    const unsigned short* __restrict__ A,    // M x K bf16
    const unsigned short* __restrict__ Bt,   // N x K bf16
    void* __restrict__ Cv,                   // M x N (fp32 or bf16)
    unsigned short* __restrict__ vmat,       // used when VSTORE
    int M, int N, int K)
{
    constexpr int MT = BM / 32;              // m-subtiles per wave
    constexpr int NT = BN / 32;
    constexpr int NSLAB = BM / 16 + BN / 16;
    const int tid  = threadIdx.x;
    const int w    = tid >> 6;
    const int lane = tid & 63;
    const int n16  = lane & 15, quad = lane >> 4;

    const int T8   = nb >> 3;                      // blocks per XCD
    const int nbid = (rbid & 7) * T8 + (rbid >> 3);
    const int gx   = N / BN;
    const int m0 = (nbid / gx) * BM;
    const int n0 = (nbid % gx) * BN;
    const int moff = (w & 1) * (MT * 16);
    const int noff = (w >> 1) * (NT * 16);

    unsigned short* As = smem_gemm;            // BM*32
    unsigned short* Bs = smem_gemm + BM*32;    // BN*32

    const unsigned short* gp[4];
    unsigned short* lp[4];
    int ns = 0;
    const int rl = lane >> 2, sc = lane & 3;
    for (int s = w; s < NSLAB; s += 4) {
        int kc = sc ^ (((s * 16 + rl) >> 1) & 3);   // XOR swizzle
        if (s < BM/16) {
            gp[ns] = A + (size_t)(m0 + s * 16 + rl) * K + kc * 8;
            lp[ns] = As + s * 512;
        } else {
            int sb = s - BM/16;
            gp[ns] = Bt + (size_t)(n0 + sb * 16 + rl) * K + kc * 8;
            lp[ns] = Bs + sb * 512;
        }
        ns++;
    }

    const int swz = (quad ^ ((n16 >> 1) & 3)) * 8;
    int aoff[MT], boff[NT];
    #pragma unroll
    for (int mt = 0; mt < MT; mt++) aoff[mt] = (moff + mt * 16 + n16) * 32 + swz;
    #pragma unroll
    for (int nt = 0; nt < NT; nt++) boff[nt] = (noff + nt * 16 + n16) * 32 + swz;

    f32x4 acc[MT][NT];
    #pragma unroll
    for (int mt = 0; mt < MT; mt++)
        #pragma unroll
        for (int nt = 0; nt < NT; nt++) acc[mt][nt] = (f32x4){0.f, 0.f, 0.f, 0.f};

    for (int k0 = 0; k0 < K; k0 += 32) {
        #pragma unroll
        for (int j = 0; j < 4; j++) if (j < ns) gl_lds16(gp[j], lp[j]);
        #pragma unroll
        for (int j = 0; j < 4; j++) if (j < ns) gp[j] += 32;
        __syncthreads();

        short8 af[MT], bfr[NT];
        #pragma unroll
        for (int mt = 0; mt < MT; mt++) af[mt] = *(const short8*)(As + aoff[mt]);
        #pragma unroll
        for (int nt = 0; nt < NT; nt++) bfr[nt] = *(const short8*)(Bs + boff[nt]);
        #pragma unroll
        for (int mt = 0; mt < MT; mt++)
            #pragma unroll
            for (int nt = 0; nt < NT; nt++)
                acc[mt][nt] = __builtin_amdgcn_mfma_f32_16x16x32_bf16(
                    af[mt], bfr[nt], acc[mt][nt], 0, 0, 0);
        __syncthreads();
    }

    if (VSTORE && ((n0 >> 7) & 1)) {
        // v-tile: write transposed into Vmat [b][h][d][token]
        const int hh = n0 >> 8;
        #pragma unroll
        for (int mt = 0; mt < MT; mt++) {
            int token = m0 + moff + mt * 16 + quad * 4;
            int bb = token >> 11, ti = token & (SEQ - 1);
            unsigned short* vb = vmat + (size_t)(bb*NH + hh) * V_DIM * SEQ + ti;
            #pragma unroll
            for (int nt = 0; nt < NT; nt++) {
                int d = noff + nt * 16 + n16;
                ushort4 u;
                u.x = f2bf(acc[mt][nt][0]); u.y = f2bf(acc[mt][nt][1]);
                u.z = f2bf(acc[mt][nt][2]); u.w = f2bf(acc[mt][nt][3]);
                *(ushort4*)(vb + (size_t)d * SEQ) = u;
            }
        }
        return;
    }

    #pragma unroll
    for (int mt = 0; mt < MT; mt++)
        #pragma unroll
        for (int nt = 0; nt < NT; nt++)
            #pragma unroll
            for (int r = 0; r < 4; r++) {
                size_t idx = (size_t)(m0 + moff + mt * 16 + quad * 4 + r) * N
                           + n0 + noff + nt * 16 + n16;
                if (OUT_BF16) ((unsigned short*)Cv)[idx] = f2bf(acc[mt][nt][r]);
                else          ((float*)Cv)[idx] = acc[mt][nt][r];
            }
}

// stage1: q_down (384 blk) || kv_down (288 blk) -- R8 geometry (BM=128)
__global__ __launch_bounds__(256) void gemm_stage1_kernel(
    const unsigned short* __restrict__ xb,
    const unsigned short* __restrict__ wt1, const unsigned short* __restrict__ wt3,
    unsigned short* __restrict__ qdb, float* __restrict__ kv_full)
{
    if (blockIdx.x < 384)
        bgemm_body<128, 128, true, false>(blockIdx.x, 384, xb, wt1, qdb, nullptr, ROWS, 1536, 2048);
    else
        bgemm_body<128, 64, false, false>(blockIdx.x - 384, 288, xb, wt3, kv_full, nullptr, ROWS, 576, 2048);
}

// stage2: q_up (768 blk) || kv_up (1024 blk, v-tiles -> Vmat transposed)
__global__ __launch_bounds__(256) void gemm_stage2_kernel(
    const unsigned short* __restrict__ qdb, const unsigned short* __restrict__ wt2,
    const unsigned short* __restrict__ kv_cb, const unsigned short* __restrict__ wt4,
    unsigned short* __restrict__ qb16, unsigned short* __restrict__ kv_exp_b,
    unsigned short* __restrict__ Vmat)
{
    if (blockIdx.x < 768)
        bgemm_body<128, 128, true, false>(blockIdx.x, 768, qdb, wt2, qb16, nullptr, ROWS, 3072, 1536);
    else
        bgemm_body<128, 128, true, true>(blockIdx.x - 768, 1024, kv_cb, wt4, kv_exp_b, Vmat, ROWS, 4096, 512);
}

// output projection -- R8 geometry (512 blocks, BM=128)
__global__ __launch_bounds__(256) void gemm_out_kernel(
    const unsigned short* __restrict__ attnb, const unsigned short* __restrict__ wt5,
    float* __restrict__ out)
{
    bgemm_body<128, 128, false, false>(blockIdx.x, 512, attnb, wt5, out, nullptr, ROWS, 2048, 2048);
}

// ---------------- RMSNorm(kv_c)->bf16 + RoPE(k_rope)->bf16 ----------------
__global__ __launch_bounds__(256) void kv_norm_rope_kernel(
    const float* __restrict__ kv_full,    // (4096, 576)
    const float* __restrict__ w,          // (512,)
    const float* __restrict__ table,
    unsigned short* __restrict__ kv_cb,   // (4096, 512) bf16
    unsigned short* __restrict__ k_rope_b)// (4096, 64) bf16 roped
{
    const int row = blockIdx.x;
    const int tid = threadIdx.x;
    const float* src = kv_full + (size_t)row * 576;
    float v0 = src[tid], v1 = src[tid + 256];
    float ss = v0*v0 + v1*v1;
    #pragma unroll
    for (int off = 32; off > 0; off >>= 1) ss += __shfl_down(ss, off);
    __shared__ float red[4];
    __shared__ float msh;
    if ((tid & 63) == 0) red[tid >> 6] = ss;
    __syncthreads();
    if (tid == 0) msh = (red[0] + red[1] + red[2] + red[3]) * (1.0f / 512.0f);
    __syncthreads();
    float f = rsqrtf(msh + 1e-6f);
    kv_cb[(size_t)row * 512 + tid]       = f2bf(v0 * f * w[tid]);
    kv_cb[(size_t)row * 512 + tid + 256] = f2bf(v1 * f * w[tid + 256]);
    if (tid < 32) {
        int pos = row & (SEQ - 1);
        float c = table[pos*64 + tid], s = table[pos*64 + 32 + tid];
        float x1 = src[512 + tid], x2 = src[512 + 32 + tid];
        k_rope_b[(size_t)row * 64 + tid]      = f2bf(x1*c - x2*s);
        k_rope_b[(size_t)row * 64 + 32 + tid] = f2bf(x2*c + x1*s);
    }
}

// ---------------- MFMA flash attention, 4-wave QBLK=64, double-buffered ------
// R7/R8 structure unchanged (proven 119 us).
__global__ __launch_bounds__(256, 3) void flash_mfma_kernel(
    const unsigned short* __restrict__ qb16,     // (4096, 3072) RAW q bf16
    const unsigned short* __restrict__ kv_exp_b, // (4096, 4096) bf16 (k-nope cols)
    const unsigned short* __restrict__ k_rope_b, // (4096, 64) bf16 roped
    const unsigned short* __restrict__ Vmat,     // [b][h][128][2048] bf16
    const float* __restrict__ table,             // (2048, 64) cos/sin
    unsigned short* __restrict__ attnb)          // (4096, 2048) bf16
{
    const int bid  = blockIdx.x;
    const int xcd  = bid & 7, slot = bid >> 3;   // XCD-clustered remap
    const int grp  = xcd + 8 * (slot >> 5);      // (b,h) group 0..31
    const int qb   = 31 - (slot & 31);           // longest blocks first
    const int h    = grp & 15, b = grp >> 4;
    const int tid  = threadIdx.x;
    const int w    = tid >> 6;
    const int lane = tid & 63;
    const int n16  = lane & 15;
    const int quad = lane >> 4;

    const int q0 = qb * 64 + w * 16;             // this wave's 16 q rows
    const char* kNopeB = (const char*)(kv_exp_b + (size_t)b * SEQ * 4096 + h * 256);
    const char* kRopeB = (const char*)(k_rope_b + (size_t)b * SEQ * 64);
    const char* vByte  = (const char*)(Vmat + (size_t)(b*NH + h) * V_DIM * SEQ);

    __shared__ unsigned short Ks[2][6144];       // 2 x 12 KB: 32 keys x 192
    __shared__ unsigned short Vs[2][4096];       // 2 x 8 KB: 128 d x 32 keys
    __shared__ unsigned short Plds[4][16][40];   // 5 KB

    // ---- per-thread staging source pointers (advance by k0 per tile) ----
    const char* gK[2]; int lK[2];
    #pragma unroll
    for (int t = 0; t < 2; t++) {
        int idx = t * 256 + tid;                 // 0..511
        int kc = idx >> 7, key = (idx >> 2) & 31, sc = idx & 3;
        int scs = sc ^ ((key >> 1) & 3);         // pre-swizzled source
        gK[t] = kNopeB + (size_t)key * 8192 + kc * 64 + scs * 16;
        lK[t] = idx * 16;
    }
    const char* gR; int lR;
    {
        int kc = tid >> 7, key = (tid >> 2) & 31, sc = tid & 3;
        int scs = sc ^ ((key >> 1) & 3);
        gR = kRopeB + (size_t)key * 128 + kc * 64 + scs * 16;
        lR = (512 + tid) * 16;
    }
    const char* gV[2]; int lV[2];
    #pragma unroll
    for (int t = 0; t < 2; t++) {
        int idx = t * 256 + tid;
        int d = idx >> 2, sc = idx & 3;
        int scs = sc ^ ((d >> 1) & 3);
        gV[t] = vByte + (size_t)d * (SEQ * 2) + scs * 16;
        lV[t] = idx * 16;
    }

    auto stage = [&](int kt, int bufsel) {
        const size_t koff = (size_t)kt * 32;
        #pragma unroll
        for (int t = 0; t < 2; t++)
            gl_lds16(gK[t] + koff * 8192, (char*)Ks[bufsel] + lK[t]);
        gl_lds16(gR + koff * 128, (char*)Ks[bufsel] + lR);
        #pragma unroll
        for (int t = 0; t < 2; t++)
            gl_lds16(gV[t] + koff * 2, (char*)Vs[bufsel] + lV[t]);
    };

    // ---- Q fragments from RAW projection output, RoPE applied in-register --
    short8 qf[6];
    {
        const unsigned short* qp = qb16 + ((size_t)(b*SEQ) + q0 + n16) * (NH*HD)
                                 + h * HD + quad * 8;
        #pragma unroll
        for (int kc = 0; kc < 6; kc++)
            qf[kc] = *(const short8*)(qp + kc * 32);
        // rope pair (128+i, 160+i), i = quad*8+j -> qf[4][j], qf[5][j]
        const float* tb = table + (size_t)(q0 + n16) * 64 + quad * 8;
        float4 c0 = *(const float4*)(tb);
        float4 c1 = *(const float4*)(tb + 4);
        float4 s0 = *(const float4*)(tb + 32);
        float4 s1 = *(const float4*)(tb + 36);
        float cs[8] = {c0.x,c0.y,c0.z,c0.w,c1.x,c1.y,c1.z,c1.w};
        float sn[8] = {s0.x,s0.y,s0.z,s0.w,s1.x,s1.y,s1.z,s1.w};
        #pragma unroll
        for (int j = 0; j < 8; j++) {
            float x1 = bf2f((unsigned short)qf[4][j]);
            float x2 = bf2f((unsigned short)qf[5][j]);
            qf[4][j] = (short)f2bf(x1*cs[j] - x2*sn[j]);
            qf[5][j] = (short)f2bf(x2*cs[j] + x1*sn[j]);
        }
    }

    // ones B-frag for the denominator MFMA (bf16 1.0 in every slot)
    short8 onesf;
    #pragma unroll
    for (int j = 0; j < 8; j++) onesf[j] = (short)0x3F80;

    f32x4 O[9];                                  // O[0..7] = out, O[8] = l
    #pragma unroll
    for (int c = 0; c < 9; c++) O[c] = (f32x4){0.f, 0.f, 0.f, 0.f};
    float mrow[4] = {-INFINITY, -INFINITY, -INFINITY, -INFINITY};

    // raw-unit softmax: exp(s*scale - m*scale) = exp2((s - m) * SCLOG2)
    const float SCLOG2 = 0.10412779736150104f;   // (1/sqrt(192))*log2(e)
    const float THRRAW = 83.14f;                 // defer-max: 6 / scale
    const int swz = (quad ^ ((n16 >> 1) & 3)) * 8;
    const int ntB = 2 * qb + 2;                  // 32-key tiles for this block

    stage(0, 0);
    int cur = 0;
    for (int kt = 0; kt < ntB; kt++) {
        __syncthreads();                          // drains stage of buf `cur`
        if (kt + 1 < ntB) stage(kt + 1, cur ^ 1); // prefetch overlaps compute
        const int k0 = kt * 32;

        if (k0 <= q0 + 15) {                      // wave-uniform causal guard
            const unsigned short* KsB = Ks[cur];
            const unsigned short* VsB = Vs[cur];

            // ---- QK^T: two 16-key halves, 6 K-chunks each ----
            f32x4 S[2];
            __builtin_amdgcn_s_setprio(1);
            #pragma unroll
            for (int half = 0; half < 2; half++) {
                f32x4 acc = (f32x4){0.f, 0.f, 0.f, 0.f};
                const int keyoff = (half * 16 + n16) * 32 + swz;
                #pragma unroll
                for (int kc = 0; kc < 6; kc++) {
                    short8 kf = *(const short8*)(KsB + kc * 1024 + keyoff);
                    acc = __builtin_amdgcn_mfma_f32_16x16x32_bf16(qf[kc], kf, acc, 0, 0, 0);
                }
                S[half] = acc;
            }
            __builtin_amdgcn_s_setprio(0);

            // ---- masks only on the diagonal tile (raw units) ----
            float p0[4], p1[4];
            if (k0 + 32 > q0) {
                #pragma unroll
                for (int r = 0; r < 4; r++) {
                    int row = q0 + quad*4 + r;
                    p0[r] = (k0 + n16      <= row) ? S[0][r] : -INFINITY;
                    p1[r] = (k0 + 16 + n16 <= row) ? S[1][r] : -INFINITY;
                }
            } else {
                #pragma unroll
                for (int r = 0; r < 4; r++) { p0[r] = S[0][r]; p1[r] = S[1][r]; }
            }

            // ---- DPP row-max + defer-max (raw units) ----
            float tmax[4];
            float growth = -INFINITY;
            #pragma unroll
            for (int r = 0; r < 4; r++) {
                tmax[r] = rowmax16(fmaxf(p0[r], p1[r]));
                growth = fmaxf(growth, tmax[r] - mrow[r]);
            }
            if (!__all(growth <= THRRAW)) {       // rescale only on real growth
                #pragma unroll
                for (int r = 0; r < 4; r++) {
                    float mnew = fmaxf(mrow[r], tmax[r]);
                    float alpha = exp2f((mrow[r] - mnew) * SCLOG2);
                    mrow[r] = mnew;
                    #pragma unroll
                    for (int c = 0; c < 9; c++) O[c][r] *= alpha;
                }
            }
            #pragma unroll
            for (int r = 0; r < 4; r++) {
                float e0 = exp2f((p0[r] - mrow[r]) * SCLOG2);  // bounded by e^6
                float e1 = exp2f((p1[r] - mrow[r]) * SCLOG2);
                unsigned int pk;
                asm("v_cvt_pk_bf16_f32 %0, %1, %2" : "=v"(pk) : "v"(e0), "v"(e1));
                unsigned short* pw = &Plds[w][quad*4 + r][0];
                pw[n16]      = (unsigned short)(pk & 0xffffu);
                pw[16 + n16] = (unsigned short)(pk >> 16);
            }

            // ---- P as A-frag (per-wave LDS roundtrip), then PV (+l) ----
            short8 pf = *(const short8*)(&Plds[w][n16][quad * 8]);
            __builtin_amdgcn_s_setprio(1);
            #pragma unroll
            for (int c = 0; c < 8; c++) {
                short8 vf = *(const short8*)(VsB + (c * 16 + n16) * 32 + swz);
                O[c] = __builtin_amdgcn_mfma_f32_16x16x32_bf16(pf, vf, O[c], 0, 0, 0);
            }
            O[8] = __builtin_amdgcn_mfma_f32_16x16x32_bf16(pf, onesf, O[8], 0, 0, 0);
            __builtin_amdgcn_s_setprio(0);
        }
        cur ^= 1;
    }

    float invl[4];
    #pragma unroll
    for (int r = 0; r < 4; r++) invl[r] = 1.0f / O[8][r];
    #pragma unroll
    for (int c = 0; c < 8; c++) {
        #pragma unroll
        for (int r = 0; r < 4; r++) {
            size_t tok = (size_t)b * SEQ + q0 + quad*4 + r;
            attnb[tok * (NH*V_DIM) + h * V_DIM + c*16 + n16] = f2bf(O[c][r] * invl[r]);
        }
    }
}

// ---------------- launch ----------------
extern "C" void kernel_launch(void* const* d_in, const int* in_sizes, int n_in,
                              void* d_out, int out_size, void* d_ws, size_t ws_size,
                              hipStream_t stream)
{
    const float* x         = (const float*)d_in[0];
    const float* w_q_down  = (const float*)d_in[1];
    const float* w_q_up    = (const float*)d_in[2];
    const float* w_kv_down = (const float*)d_in[3];
    const float* kv_norm_w = (const float*)d_in[4];
    const float* w_kv_up   = (const float*)d_in[5];
    const float* w_out     = (const float*)d_in[6];
    float* out = (float*)d_out;
    float* ws  = (float*)d_ws;

    // ---- workspace layout (float offsets), total 41,746,432 floats (~167 MB) ----
    float*          table    = ws;                                // 131072
    unsigned short* xb       = (unsigned short*)(ws + 131072);    // 4096x2048 bf16
    unsigned short* qdb      = (unsigned short*)(ws + 4325376);   // 4096x1536 bf16
    unsigned short* qb16     = (unsigned short*)(ws + 7471104);   // 4096x3072 bf16
    float*          kv_full  = ws + 13762560;                     // 4096x576 fp32
    unsigned short* kv_cb    = (unsigned short*)(ws + 16121856);  // 4096x512 bf16
    unsigned short* k_rope_b = (unsigned short*)(ws + 17170432);  // 4096x64 bf16
    unsigned short* kv_exp_b = (unsigned short*)(ws + 17301504);  // 4096x4096 bf16
    unsigned short* Vmat     = (unsigned short*)(ws + 25690112);  // 2x16x128x2048 bf16
    unsigned short* attnb    = (unsigned short*)(ws + 29884416);  // 4096x2048 bf16
    unsigned short* wt1      = (unsigned short*)(ws + 34078720);  // 1536x2048
    unsigned short* wt2      = (unsigned short*)(ws + 35651584);  // 3072x1536
    unsigned short* wt3      = (unsigned short*)(ws + 38010880);  // 576x2048
    unsigned short* wt4      = (unsigned short*)(ws + 38600704);  // 4096x512
    unsigned short* wt5      = (unsigned short*)(ws + 39649280);  // 2048x2048 -> end 41746432

    // all independent preprocessing in ONE launch
    preprocess_kernel<<<dim3(12448), 256, 0, stream>>>(
        x, w_q_down, w_q_up, w_kv_down, w_kv_up, w_out,
        table, xb, wt1, wt2, wt3, wt4, wt5);

    // stage1: q_down || kv_down (672 blocks, BM=128 -- R8 geometry)
    gemm_stage1_kernel<<<dim3(672), 256, 16384, stream>>>(xb, wt1, wt3, qdb, kv_full);

    kv_norm_rope_kernel<<<ROWS, 256, 0, stream>>>(kv_full, kv_norm_w, table, kv_cb, k_rope_b);

    // stage2: q_up || kv_up (v-tiles written transposed into Vmat; pack_vt gone)
    gemm_stage2_kernel<<<dim3(1792), 256, 16384, stream>>>(qdb, wt2, kv_cb, wt4, qb16, kv_exp_b, Vmat);

    // attention (R7 structure, unchanged)
    flash_mfma_kernel<<<dim3(1024), 256, 0, stream>>>(qb16, kv_exp_b, k_rope_b, Vmat, table, attnb);

    // output projection (512 blocks, BM=128 -- R8 geometry)
    gemm_out_kernel<<<dim3(512), 256, 16384, stream>>>(attnb, wt5, out);
}

// Round 12
// 416.457 us; speedup vs baseline: 1.1231x; 1.0453x over previous
//
#include <hip/hip_runtime.h>
#include <hip/hip_bf16.h>
#include <math.h>

// ---------------- problem constants ----------------
#define HID    2048
#define NH     16
#define D_NOPE 128
#define D_ROPE 64
#define HD     192      // HEAD_DIM
#define V_DIM  128
#define KV_RANK 512
#define Q_RANK  1536
#define BATCH  2
#define SEQ    2048
#define ROWS   (BATCH*SEQ)   // 4096

typedef __attribute__((ext_vector_type(8))) short short8;
typedef __attribute__((ext_vector_type(4))) float f32x4;

__device__ __forceinline__ unsigned short f2bf(float x) {
    unsigned int u = __float_as_uint(x);
    unsigned int r = (u + 0x7fffu + ((u >> 16) & 1u)) >> 16;
    return (unsigned short)r;
}
__device__ __forceinline__ float bf2f(unsigned short u) {
    return __uint_as_float((unsigned int)u << 16);
}

typedef const __attribute__((address_space(1))) unsigned int gu32;
typedef __attribute__((address_space(3))) unsigned int lu32;
__device__ __forceinline__ void gl_lds16(const void* g, void* l) {
    __builtin_amdgcn_global_load_lds((gu32*)g, (lu32*)l, 16, 0, 0);
}

// DPP lane permute within a 16-lane row (VALU pipe, no LDS traffic)
template<int CTRL>
__device__ __forceinline__ float dpp_mv(float x) {
    return __int_as_float(__builtin_amdgcn_update_dpp(
        __float_as_int(x), __float_as_int(x), CTRL, 0xF, 0xF, true));
}
// max over the 16 contiguous lanes of a DPP row
__device__ __forceinline__ float rowmax16(float x) {
    x = fmaxf(x, dpp_mv<0xB1>(x));   // quad_perm [1,0,3,2]  (xor 1)
    x = fmaxf(x, dpp_mv<0x4E>(x));   // quad_perm [2,3,0,1]  (xor 2)
    x = fmaxf(x, dpp_mv<0x141>(x));  // row_half_mirror      (combine quads)
    x = fmaxf(x, dpp_mv<0x140>(x));  // row_mirror           (combine halves)
    return x;
}

// ---------------- fused preprocessing: rope table + x->bf16 + 5 transposes ---
__global__ __launch_bounds__(256) void preprocess_kernel(
    const float* __restrict__ x,
    const float* __restrict__ w_q_down, const float* __restrict__ w_q_up,
    const float* __restrict__ w_kv_down, const float* __restrict__ w_kv_up,
    const float* __restrict__ w_out,
    float* __restrict__ table, unsigned short* __restrict__ xb,
    unsigned short* __restrict__ wt1, unsigned short* __restrict__ wt2,
    unsigned short* __restrict__ wt3, unsigned short* __restrict__ wt4,
    unsigned short* __restrict__ wt5)
{
    const int tid = threadIdx.x;
    int bid = blockIdx.x;

    if (bid < 512) {                       // ---- RoPE cos/sin table ----
        int idx = bid * 256 + tid;         // < 2048*64
        int pos = idx >> 6, u = idx & 63;
        int i = u & 31;
        float invf = expf((float)i * (-9.210340371976184f / 32.0f));
        float ang = (float)pos * invf;
        table[idx] = (u < 32) ? cosf(ang) : sinf(ang);
        return;
    }
    bid -= 512;
    if (bid < 8192) {                      // ---- x fp32 -> bf16 ----
        size_t i = (size_t)(bid * 256 + tid) * 4;
        float4 v = *(const float4*)(x + i);
        ushort4 u;
        u.x = f2bf(v.x); u.y = f2bf(v.y); u.z = f2bf(v.z); u.w = f2bf(v.w);
        *(ushort4*)(xb + i) = u;
        return;
    }
    bid -= 8192;

    // ---- weight transposes: fp32 (K x N) -> bf16 (N x K) ----
    const float* src; unsigned short* dst; int K, N, gx, lb;
    if (bid < 768)       { src = w_q_down;  dst = wt1; K = 2048; N = 1536; gx = 24; lb = bid; }
    else if (bid < 1920) { src = w_q_up;    dst = wt2; K = 1536; N = 3072; gx = 48; lb = bid - 768; }
    else if (bid < 2208) { src = w_kv_down; dst = wt3; K = 2048; N = 576;  gx = 9;  lb = bid - 1920; }
    else if (bid < 2720) { src = w_kv_up;   dst = wt4; K = 512;  N = 4096; gx = 64; lb = bid - 2208; }
    else                 { src = w_out;     dst = wt5; K = 2048; N = 2048; gx = 32; lb = bid - 2720; }
    const int n0 = (lb % gx) * 64, k0 = (lb / gx) * 64;

    __shared__ float T[64][65];
    const int c4 = tid & 15, r = tid >> 4;
    #pragma unroll
    for (int i = 0; i < 4; i++) {
        int row = r + i * 16;
        float4 v = *(const float4*)(src + (size_t)(k0 + row) * N + n0 + c4 * 4);
        T[row][c4*4+0] = v.x; T[row][c4*4+1] = v.y;
        T[row][c4*4+2] = v.z; T[row][c4*4+3] = v.w;
    }
    __syncthreads();
    #pragma unroll
    for (int i = 0; i < 4; i++) {
        int nrow = r + i * 16;
        ushort4 u;
        u.x = f2bf(T[c4*4+0][nrow]); u.y = f2bf(T[c4*4+1][nrow]);
        u.z = f2bf(T[c4*4+2][nrow]); u.w = f2bf(T[c4*4+3][nrow]);
        *(ushort4*)(dst + (size_t)(n0 + nrow) * K + k0 + c4 * 4) = u;
    }
}

// ---------------- bf16 MFMA GEMM body: C(M,N) = A(M,K) @ Bt(N,K)^T ----------
// BM=128, double-buffered LDS with one-tile-ahead prefetch (T3-lite, same
// schedule proven in flash R1->R3): per K-step {barrier; prefetch(k+1 ->
// buf^1); ds_read+MFMA(buf)}.  NOTE: dynamic-LDS buffers must be addressed
// by runtime offset (smem_gemm + sel*HALF) -- an array of pointers into
// extern __shared__ fails to compile (addrspacecast static-initializer).
extern __shared__ unsigned short smem_gemm[];   // 2 x (BM+BN)*32 bf16

template<int BM, int BN, bool OUT_BF16, bool VSTORE>
__device__ __forceinline__ void bgemm_body(
    int rbid, int nb,
    const unsigned short* __restrict__ A,    // M x K bf16
    const unsigned short* __restrict__ Bt,   // N x K bf16
    void* __restrict__ Cv,                   // M x N (fp32 or bf16)
    unsigned short* __restrict__ vmat,       // used when VSTORE
    int M, int N, int K)
{
    constexpr int MT = BM / 32;              // m-subtiles per wave
    constexpr int NT = BN / 32;
    constexpr int NSLAB = BM / 16 + BN / 16;
    constexpr int HALF = (BM + BN) * 32;     // elements per LDS buffer
    const int tid  = threadIdx.x;
    const int w    = tid >> 6;
    const int lane = tid & 63;
    const int n16  = lane & 15, quad = lane >> 4;

    const int T8   = nb >> 3;                      // blocks per XCD
    const int nbid = (rbid & 7) * T8 + (rbid >> 3);
    const int gx   = N / BN;
    const int m0 = (nbid / gx) * BM;
    const int n0 = (nbid % gx) * BN;
    const int moff = (w & 1) * (MT * 16);
    const int noff = (w >> 1) * (NT * 16);

    const unsigned short* gp[4];
    int lo[4];                               // element offset within a buffer
    int ns = 0;
    const int rl = lane >> 2, sc = lane & 3;
    for (int s = w; s < NSLAB; s += 4) {
        int kc = sc ^ (((s * 16 + rl) >> 1) & 3);   // XOR swizzle
        if (s < BM/16) {
            gp[ns] = A + (size_t)(m0 + s * 16 + rl) * K + kc * 8;
            lo[ns] = s * 512;
        } else {
            int sb = s - BM/16;
            gp[ns] = Bt + (size_t)(n0 + sb * 16 + rl) * K + kc * 8;
            lo[ns] = BM * 32 + sb * 512;
        }
        ns++;
    }

    const int swz = (quad ^ ((n16 >> 1) & 3)) * 8;
    int aoff[MT], boff[NT];
    #pragma unroll
    for (int mt = 0; mt < MT; mt++) aoff[mt] = (moff + mt * 16 + n16) * 32 + swz;
    #pragma unroll
    for (int nt = 0; nt < NT; nt++) boff[nt] = BM * 32 + (noff + nt * 16 + n16) * 32 + swz;

    f32x4 acc[MT][NT];
    #pragma unroll
    for (int mt = 0; mt < MT; mt++)
        #pragma unroll
        for (int nt = 0; nt < NT; nt++) acc[mt][nt] = (f32x4){0.f, 0.f, 0.f, 0.f};

    auto stage = [&](int bufsel) {
        unsigned short* dstb = smem_gemm + bufsel * HALF;
        #pragma unroll
        for (int j = 0; j < 4; j++) if (j < ns) gl_lds16(gp[j], dstb + lo[j]);
        #pragma unroll
        for (int j = 0; j < 4; j++) if (j < ns) gp[j] += 32;
    };

    stage(0);                                 // prologue: stage tile 0
    int cur = 0;
    for (int k0 = 0; k0 < K; k0 += 32) {
        __syncthreads();                      // drains stage of buf `cur`
        if (k0 + 32 < K) stage(cur ^ 1);      // prefetch overlaps compute

        const unsigned short* B = smem_gemm + cur * HALF;
        short8 af[MT], bfr[NT];
        #pragma unroll
        for (int mt = 0; mt < MT; mt++) af[mt] = *(const short8*)(B + aoff[mt]);
        #pragma unroll
        for (int nt = 0; nt < NT; nt++) bfr[nt] = *(const short8*)(B + boff[nt]);
        #pragma unroll
        for (int mt = 0; mt < MT; mt++)
            #pragma unroll
            for (int nt = 0; nt < NT; nt++)
                acc[mt][nt] = __builtin_amdgcn_mfma_f32_16x16x32_bf16(
                    af[mt], bfr[nt], acc[mt][nt], 0, 0, 0);
        cur ^= 1;
    }

    if (VSTORE && ((n0 >> 7) & 1)) {
        // v-tile: write transposed into Vmat [b][h][d][token]
        const int hh = n0 >> 8;
        #pragma unroll
        for (int mt = 0; mt < MT; mt++) {
            int token = m0 + moff + mt * 16 + quad * 4;
            int bb = token >> 11, ti = token & (SEQ - 1);
            unsigned short* vb = vmat + (size_t)(bb*NH + hh) * V_DIM * SEQ + ti;
            #pragma unroll
            for (int nt = 0; nt < NT; nt++) {
                int d = noff + nt * 16 + n16;
                ushort4 u;
                u.x = f2bf(acc[mt][nt][0]); u.y = f2bf(acc[mt][nt][1]);
                u.z = f2bf(acc[mt][nt][2]); u.w = f2bf(acc[mt][nt][3]);
                *(ushort4*)(vb + (size_t)d * SEQ) = u;
            }
        }
        return;
    }

    #pragma unroll
    for (int mt = 0; mt < MT; mt++)
        #pragma unroll
        for (int nt = 0; nt < NT; nt++)
            #pragma unroll
            for (int r = 0; r < 4; r++) {
                size_t idx = (size_t)(m0 + moff + mt * 16 + quad * 4 + r) * N
                           + n0 + noff + nt * 16 + n16;
                if (OUT_BF16) ((unsigned short*)Cv)[idx] = f2bf(acc[mt][nt][r]);
                else          ((float*)Cv)[idx] = acc[mt][nt][r];
            }
}

// stage1: q_down (384 blk) || kv_down (288 blk), BM=128
__global__ __launch_bounds__(256) void gemm_stage1_kernel(
    const unsigned short* __restrict__ xb,
    const unsigned short* __restrict__ wt1, const unsigned short* __restrict__ wt3,
    unsigned short* __restrict__ qdb, float* __restrict__ kv_full)
{
    if (blockIdx.x < 384)
        bgemm_body<128, 128, true, false>(blockIdx.x, 384, xb, wt1, qdb, nullptr, ROWS, 1536, 2048);
    else
        bgemm_body<128, 64, false, false>(blockIdx.x - 384, 288, xb, wt3, kv_full, nullptr, ROWS, 576, 2048);
}

// stage2: q_up (768 blk) || kv_up (1024 blk, v-tiles -> Vmat transposed)
__global__ __launch_bounds__(256) void gemm_stage2_kernel(
    const unsigned short* __restrict__ qdb, const unsigned short* __restrict__ wt2,
    const unsigned short* __restrict__ kv_cb, const unsigned short* __restrict__ wt4,
    unsigned short* __restrict__ qb16, unsigned short* __restrict__ kv_exp_b,
    unsigned short* __restrict__ Vmat)
{
    if (blockIdx.x < 768)
        bgemm_body<128, 128, true, false>(blockIdx.x, 768, qdb, wt2, qb16, nullptr, ROWS, 3072, 1536);
    else
        bgemm_body<128, 128, true, true>(blockIdx.x - 768, 1024, kv_cb, wt4, kv_exp_b, Vmat, ROWS, 4096, 512);
}

// output projection (512 blocks, BM=128)
__global__ __launch_bounds__(256) void gemm_out_kernel(
    const unsigned short* __restrict__ attnb, const unsigned short* __restrict__ wt5,
    float* __restrict__ out)
{
    bgemm_body<128, 128, false, false>(blockIdx.x, 512, attnb, wt5, out, nullptr, ROWS, 2048, 2048);
}

// ---------------- RMSNorm(kv_c)->bf16 + RoPE(k_rope)->bf16 ----------------
__global__ __launch_bounds__(256) void kv_norm_rope_kernel(
    const float* __restrict__ kv_full,    // (4096, 576)
    const float* __restrict__ w,          // (512,)
    const float* __restrict__ table,
    unsigned short* __restrict__ kv_cb,   // (4096, 512) bf16
    unsigned short* __restrict__ k_rope_b)// (4096, 64) bf16 roped
{
    const int row = blockIdx.x;
    const int tid = threadIdx.x;
    const float* src = kv_full + (size_t)row * 576;
    float v0 = src[tid], v1 = src[tid + 256];
    float ss = v0*v0 + v1*v1;
    #pragma unroll
    for (int off = 32; off > 0; off >>= 1) ss += __shfl_down(ss, off);
    __shared__ float red[4];
    __shared__ float msh;
    if ((tid & 63) == 0) red[tid >> 6] = ss;
    __syncthreads();
    if (tid == 0) msh = (red[0] + red[1] + red[2] + red[3]) * (1.0f / 512.0f);
    __syncthreads();
    float f = rsqrtf(msh + 1e-6f);
    kv_cb[(size_t)row * 512 + tid]       = f2bf(v0 * f * w[tid]);
    kv_cb[(size_t)row * 512 + tid + 256] = f2bf(v1 * f * w[tid + 256]);
    if (tid < 32) {
        int pos = row & (SEQ - 1);
        float c = table[pos*64 + tid], s = table[pos*64 + 32 + tid];
        float x1 = src[512 + tid], x2 = src[512 + 32 + tid];
        k_rope_b[(size_t)row * 64 + tid]      = f2bf(x1*c - x2*s);
        k_rope_b[(size_t)row * 64 + 32 + tid] = f2bf(x2*c + x1*s);
    }
}

// ---------------- MFMA flash attention, 4-wave QBLK=64, double-buffered ------
// R7/R8 structure unchanged (proven 119 us).
__global__ __launch_bounds__(256, 3) void flash_mfma_kernel(
    const unsigned short* __restrict__ qb16,     // (4096, 3072) RAW q bf16
    const unsigned short* __restrict__ kv_exp_b, // (4096, 4096) bf16 (k-nope cols)
    const unsigned short* __restrict__ k_rope_b, // (4096, 64) bf16 roped
    const unsigned short* __restrict__ Vmat,     // [b][h][128][2048] bf16
    const float* __restrict__ table,             // (2048, 64) cos/sin
    unsigned short* __restrict__ attnb)          // (4096, 2048) bf16
{
    const int bid  = blockIdx.x;
    const int xcd  = bid & 7, slot = bid >> 3;   // XCD-clustered remap
    const int grp  = xcd + 8 * (slot >> 5);      // (b,h) group 0..31
    const int qb   = 31 - (slot & 31);           // longest blocks first
    const int h    = grp & 15, b = grp >> 4;
    const int tid  = threadIdx.x;
    const int w    = tid >> 6;
    const int lane = tid & 63;
    const int n16  = lane & 15;
    const int quad = lane >> 4;

    const int q0 = qb * 64 + w * 16;             // this wave's 16 q rows
    const char* kNopeB = (const char*)(kv_exp_b + (size_t)b * SEQ * 4096 + h * 256);
    const char* kRopeB = (const char*)(k_rope_b + (size_t)b * SEQ * 64);
    const char* vByte  = (const char*)(Vmat + (size_t)(b*NH + h) * V_DIM * SEQ);

    __shared__ unsigned short Ks[2][6144];       // 2 x 12 KB: 32 keys x 192
    __shared__ unsigned short Vs[2][4096];       // 2 x 8 KB: 128 d x 32 keys
    __shared__ unsigned short Plds[4][16][40];   // 5 KB

    // ---- per-thread staging source pointers (advance by k0 per tile) ----
    const char* gK[2]; int lK[2];
    #pragma unroll
    for (int t = 0; t < 2; t++) {
        int idx = t * 256 + tid;                 // 0..511
        int kc = idx >> 7, key = (idx >> 2) & 31, sc = idx & 3;
        int scs = sc ^ ((key >> 1) & 3);         // pre-swizzled source
        gK[t] = kNopeB + (size_t)key * 8192 + kc * 64 + scs * 16;
        lK[t] = idx * 16;
    }
    const char* gR; int lR;
    {
        int kc = tid >> 7, key = (tid >> 2) & 31, sc = tid & 3;
        int scs = sc ^ ((key >> 1) & 3);
        gR = kRopeB + (size_t)key * 128 + kc * 64 + scs * 16;
        lR = (512 + tid) * 16;
    }
    const char* gV[2]; int lV[2];
    #pragma unroll
    for (int t = 0; t < 2; t++) {
        int idx = t * 256 + tid;
        int d = idx >> 2, sc = idx & 3;
        int scs = sc ^ ((d >> 1) & 3);
        gV[t] = vByte + (size_t)d * (SEQ * 2) + scs * 16;
        lV[t] = idx * 16;
    }

    auto stage = [&](int kt, int bufsel) {
        const size_t koff = (size_t)kt * 32;
        #pragma unroll
        for (int t = 0; t < 2; t++)
            gl_lds16(gK[t] + koff * 8192, (char*)Ks[bufsel] + lK[t]);
        gl_lds16(gR + koff * 128, (char*)Ks[bufsel] + lR);
        #pragma unroll
        for (int t = 0; t < 2; t++)
            gl_lds16(gV[t] + koff * 2, (char*)Vs[bufsel] + lV[t]);
    };

    // ---- Q fragments from RAW projection output, RoPE applied in-register --
    short8 qf[6];
    {
        const unsigned short* qp = qb16 + ((size_t)(b*SEQ) + q0 + n16) * (NH*HD)
                                 + h * HD + quad * 8;
        #pragma unroll
        for (int kc = 0; kc < 6; kc++)
            qf[kc] = *(const short8*)(qp + kc * 32);
        // rope pair (128+i, 160+i), i = quad*8+j -> qf[4][j], qf[5][j]
        const float* tb = table + (size_t)(q0 + n16) * 64 + quad * 8;
        float4 c0 = *(const float4*)(tb);
        float4 c1 = *(const float4*)(tb + 4);
        float4 s0 = *(const float4*)(tb + 32);
        float4 s1 = *(const float4*)(tb + 36);
        float cs[8] = {c0.x,c0.y,c0.z,c0.w,c1.x,c1.y,c1.z,c1.w};
        float sn[8] = {s0.x,s0.y,s0.z,s0.w,s1.x,s1.y,s1.z,s1.w};
        #pragma unroll
        for (int j = 0; j < 8; j++) {
            float x1 = bf2f((unsigned short)qf[4][j]);
            float x2 = bf2f((unsigned short)qf[5][j]);
            qf[4][j] = (short)f2bf(x1*cs[j] - x2*sn[j]);
            qf[5][j] = (short)f2bf(x2*cs[j] + x1*sn[j]);
        }
    }

    // ones B-frag for the denominator MFMA (bf16 1.0 in every slot)
    short8 onesf;
    #pragma unroll
    for (int j = 0; j < 8; j++) onesf[j] = (short)0x3F80;

    f32x4 O[9];                                  // O[0..7] = out, O[8] = l
    #pragma unroll
    for (int c = 0; c < 9; c++) O[c] = (f32x4){0.f, 0.f, 0.f, 0.f};
    float mrow[4] = {-INFINITY, -INFINITY, -INFINITY, -INFINITY};

    // raw-unit softmax: exp(s*scale - m*scale) = exp2((s - m) * SCLOG2)
    const float SCLOG2 = 0.10412779736150104f;   // (1/sqrt(192))*log2(e)
    const float THRRAW = 83.14f;                 // defer-max: 6 / scale
    const int swz = (quad ^ ((n16 >> 1) & 3)) * 8;
    const int ntB = 2 * qb + 2;                  // 32-key tiles for this block

    stage(0, 0);
    int cur = 0;
    for (int kt = 0; kt < ntB; kt++) {
        __syncthreads();                          // drains stage of buf `cur`
        if (kt + 1 < ntB) stage(kt + 1, cur ^ 1); // prefetch overlaps compute
        const int k0 = kt * 32;

        if (k0 <= q0 + 15) {                      // wave-uniform causal guard
            const unsigned short* KsB = Ks[cur];
            const unsigned short* VsB = Vs[cur];

            // ---- QK^T: two 16-key halves, 6 K-chunks each ----
            f32x4 S[2];
            __builtin_amdgcn_s_setprio(1);
            #pragma unroll
            for (int half = 0; half < 2; half++) {
                f32x4 acc = (f32x4){0.f, 0.f, 0.f, 0.f};
                const int keyoff = (half * 16 + n16) * 32 + swz;
                #pragma unroll
                for (int kc = 0; kc < 6; kc++) {
                    short8 kf = *(const short8*)(KsB + kc * 1024 + keyoff);
                    acc = __builtin_amdgcn_mfma_f32_16x16x32_bf16(qf[kc], kf, acc, 0, 0, 0);
                }
                S[half] = acc;
            }
            __builtin_amdgcn_s_setprio(0);

            // ---- masks only on the diagonal tile (raw units) ----
            float p0[4], p1[4];
            if (k0 + 32 > q0) {
                #pragma unroll
                for (int r = 0; r < 4; r++) {
                    int row = q0 + quad*4 + r;
                    p0[r] = (k0 + n16      <= row) ? S[0][r] : -INFINITY;
                    p1[r] = (k0 + 16 + n16 <= row) ? S[1][r] : -INFINITY;
                }
            } else {
                #pragma unroll
                for (int r = 0; r < 4; r++) { p0[r] = S[0][r]; p1[r] = S[1][r]; }
            }

            // ---- DPP row-max + defer-max (raw units) ----
            float tmax[4];
            float growth = -INFINITY;
            #pragma unroll
            for (int r = 0; r < 4; r++) {
                tmax[r] = rowmax16(fmaxf(p0[r], p1[r]));
                growth = fmaxf(growth, tmax[r] - mrow[r]);
            }
            if (!__all(growth <= THRRAW)) {       // rescale only on real growth
                #pragma unroll
                for (int r = 0; r < 4; r++) {
                    float mnew = fmaxf(mrow[r], tmax[r]);
                    float alpha = exp2f((mrow[r] - mnew) * SCLOG2);
                    mrow[r] = mnew;
                    #pragma unroll
                    for (int c = 0; c < 9; c++) O[c][r] *= alpha;
                }
            }
            #pragma unroll
            for (int r = 0; r < 4; r++) {
                float e0 = exp2f((p0[r] - mrow[r]) * SCLOG2);  // bounded by e^6
                float e1 = exp2f((p1[r] - mrow[r]) * SCLOG2);
                unsigned int pk;
                asm("v_cvt_pk_bf16_f32 %0, %1, %2" : "=v"(pk) : "v"(e0), "v"(e1));
                unsigned short* pw = &Plds[w][quad*4 + r][0];
                pw[n16]      = (unsigned short)(pk & 0xffffu);
                pw[16 + n16] = (unsigned short)(pk >> 16);
            }

            // ---- P as A-frag (per-wave LDS roundtrip), then PV (+l) ----
            short8 pf = *(const short8*)(&Plds[w][n16][quad * 8]);
            __builtin_amdgcn_s_setprio(1);
            #pragma unroll
            for (int c = 0; c < 8; c++) {
                short8 vf = *(const short8*)(VsB + (c * 16 + n16) * 32 + swz);
                O[c] = __builtin_amdgcn_mfma_f32_16x16x32_bf16(pf, vf, O[c], 0, 0, 0);
            }
            O[8] = __builtin_amdgcn_mfma_f32_16x16x32_bf16(pf, onesf, O[8], 0, 0, 0);
            __builtin_amdgcn_s_setprio(0);
        }
        cur ^= 1;
    }

    float invl[4];
    #pragma unroll
    for (int r = 0; r < 4; r++) invl[r] = 1.0f / O[8][r];
    #pragma unroll
    for (int c = 0; c < 8; c++) {
        #pragma unroll
        for (int r = 0; r < 4; r++) {
            size_t tok = (size_t)b * SEQ + q0 + quad*4 + r;
            attnb[tok * (NH*V_DIM) + h * V_DIM + c*16 + n16] = f2bf(O[c][r] * invl[r]);
        }
    }
}

// ---------------- launch ----------------
extern "C" void kernel_launch(void* const* d_in, const int* in_sizes, int n_in,
                              void* d_out, int out_size, void* d_ws, size_t ws_size,
                              hipStream_t stream)
{
    const float* x         = (const float*)d_in[0];
    const float* w_q_down  = (const float*)d_in[1];
    const float* w_q_up    = (const float*)d_in[2];
    const float* w_kv_down = (const float*)d_in[3];
    const float* kv_norm_w = (const float*)d_in[4];
    const float* w_kv_up   = (const float*)d_in[5];
    const float* w_out     = (const float*)d_in[6];
    float* out = (float*)d_out;
    float* ws  = (float*)d_ws;

    // ---- workspace layout (float offsets), total 41,746,432 floats (~167 MB) ----
    float*          table    = ws;                                // 131072
    unsigned short* xb       = (unsigned short*)(ws + 131072);    // 4096x2048 bf16
    unsigned short* qdb      = (unsigned short*)(ws + 4325376);   // 4096x1536 bf16
    unsigned short* qb16     = (unsigned short*)(ws + 7471104);   // 4096x3072 bf16
    float*          kv_full  = ws + 13762560;                     // 4096x576 fp32
    unsigned short* kv_cb    = (unsigned short*)(ws + 16121856);  // 4096x512 bf16
    unsigned short* k_rope_b = (unsigned short*)(ws + 17170432);  // 4096x64 bf16
    unsigned short* kv_exp_b = (unsigned short*)(ws + 17301504);  // 4096x4096 bf16
    unsigned short* Vmat     = (unsigned short*)(ws + 25690112);  // 2x16x128x2048 bf16
    unsigned short* attnb    = (unsigned short*)(ws + 29884416);  // 4096x2048 bf16
    unsigned short* wt1      = (unsigned short*)(ws + 34078720);  // 1536x2048
    unsigned short* wt2      = (unsigned short*)(ws + 35651584);  // 3072x1536
    unsigned short* wt3      = (unsigned short*)(ws + 38010880);  // 576x2048
    unsigned short* wt4      = (unsigned short*)(ws + 38600704);  // 4096x512
    unsigned short* wt5      = (unsigned short*)(ws + 39649280);  // 2048x2048 -> end 41746432

    // all independent preprocessing in ONE launch
    preprocess_kernel<<<dim3(12448), 256, 0, stream>>>(
        x, w_q_down, w_q_up, w_kv_down, w_kv_up, w_out,
        table, xb, wt1, wt2, wt3, wt4, wt5);

    // stage1: q_down || kv_down (672 blocks, dbuf LDS = 2x12 KB max)
    gemm_stage1_kernel<<<dim3(672), 256, 32768, stream>>>(xb, wt1, wt3, qdb, kv_full);

    kv_norm_rope_kernel<<<ROWS, 256, 0, stream>>>(kv_full, kv_norm_w, table, kv_cb, k_rope_b);

    // stage2: q_up || kv_up (dbuf 2x16 KB; v-tiles -> Vmat transposed)
    gemm_stage2_kernel<<<dim3(1792), 256, 32768, stream>>>(qdb, wt2, kv_cb, wt4, qb16, kv_exp_b, Vmat);

    // attention (R7 structure, unchanged)
    flash_mfma_kernel<<<dim3(1024), 256, 0, stream>>>(qb16, kv_exp_b, k_rope_b, Vmat, table, attnb);

    // output projection (512 blocks, dbuf 2x16 KB)
    gemm_out_kernel<<<dim3(512), 256, 32768, stream>>>(attnb, wt5, out);
}